// Round 1
// baseline (273.936 us; speedup 1.0000x reference)
//
#include <hip/hip_runtime.h>

#define LVL 16
#define FEAT 4
#define HSZ 524288            // 2^19
#define HMASK (HSZ - 1)
#define P1 73856093u
#define P2 19349663u

// round(np.logspace(log10(16), log10(1024), 16)) -- verified by hand:
// r_l = 16 * 2^(0.4*l)
static __device__ __constant__ int kRes[LVL] = {
    16, 21, 28, 37, 49, 64, 84, 111, 147, 194, 256, 338, 446, 588, 776, 1024
};

__global__ void __launch_bounds__(256)
hashgrid1d_kernel(const float* __restrict__ x,
                  const float* __restrict__ tables,
                  float* __restrict__ out,
                  int B)
{
    const int tid    = blockIdx.x * blockDim.x + threadIdx.x;
    const int stride = gridDim.x * blockDim.x;      // multiple of 16

    // level is loop-invariant (stride % 16 == 0): hoist everything per-level
    const int      l     = tid & 15;
    const int      res   = kRes[l];
    const float    resm1 = (float)(res - 1);
    const int      imax  = res - 1;
    const unsigned lh    = (unsigned)l * P2;        // l*P2 fits in 31 bits
    const float*   tbase = tables + (size_t)l * (size_t)HSZ * FEAT;

    const int total = B * LVL;
    for (int idx = tid; idx < total; idx += stride) {
        const int p = idx >> 4;                     // point index

        float xc = x[p];
        xc = fminf(fmaxf(xc, 0.0f), 1.0f);

        const float t  = xc * resm1;                // f32, same as reference
        const float fi = floorf(t);
        const int   i0 = (int)fi;
        const int   i1 = min(i0 + 1, imax);
        const float w  = t - fi;

        // int32-wrap mul + xor, floored mod 2^19 == mask on two's-complement bits
        const unsigned h0 = (((unsigned)i0 * P1) ^ lh) & HMASK;
        const unsigned h1 = (((unsigned)i1 * P1) ^ lh) & HMASK;

        const float4 e0 = *(const float4*)(tbase + (size_t)h0 * FEAT);
        const float4 e1 = *(const float4*)(tbase + (size_t)h1 * FEAT);

        const float omw = 1.0f - w;
        float4 r;
        r.x = e0.x * omw + e1.x * w;
        r.y = e0.y * omw + e1.y * w;
        r.z = e0.z * omw + e1.z * w;
        r.w = e0.w * omw + e1.w * w;

        // out[p*64 + l*4 .. +3] == out[idx*4 .. +3]; wave writes 1 KiB contiguous
        *(float4*)(out + (size_t)idx * FEAT) = r;
    }
}

extern "C" void kernel_launch(void* const* d_in, const int* in_sizes, int n_in,
                              void* d_out, int out_size, void* d_ws, size_t ws_size,
                              hipStream_t stream)
{
    const float* x      = (const float*)d_in[0];
    const float* tables = (const float*)d_in[1];
    float*       out    = (float*)d_out;
    const int    B      = in_sizes[0];              // 2097152

    // memory-bound: ~2048 blocks, grid-stride (64 items/thread)
    dim3 grid(2048), block(256);
    hipLaunchKernelGGL(hashgrid1d_kernel, grid, block, 0, stream,
                       x, tables, out, B);
}

// Round 3
// 113.846 us; speedup vs baseline: 2.4062x; 2.4062x over previous
//
#include <hip/hip_runtime.h>

#define LVL 16
#define FEAT 4
#define HSZ 524288            // 2^19
#define HMASK (HSZ - 1)
#define P1 73856093u
#define P2 19349663u

#define NSTAGE 3155           // sum of res[0..14]; level 15 (1024) stays in global
#define BLOCK 1024
#define GRID 512              // 512*1024 threads = 2 blocks/CU on 256 CUs

typedef float f32x4 __attribute__((ext_vector_type(4)));   // native vec: NT-store OK

// round(np.logspace(log10(16), log10(1024), 16)):
static __device__ __constant__ int kRes[LVL] = {
    16, 21, 28, 37, 49, 64, 84, 111, 147, 194, 256, 338, 446, 588, 776, 1024
};
// exclusive prefix sum of kRes[0..14] (dense LDS offsets); level 15 unstaged
static __device__ __constant__ int kOff[15] = {
    0, 16, 37, 65, 102, 151, 215, 299, 410, 557, 751, 1007, 1345, 1791, 2379
};

__global__ void __launch_bounds__(BLOCK)
hashgrid1d_kernel(const float* __restrict__ x,
                  const float* __restrict__ tables,
                  float* __restrict__ out,
                  int B)
{
    __shared__ f32x4 sTab[NSTAGE];   // 50,480 B

    // ---- stage: de-hash levels 0..14 into a dense LDS table (once per block)
    for (int e = threadIdx.x; e < NSTAGE; e += BLOCK) {
        int l = 0;
        #pragma unroll
        for (int k = 1; k < 15; ++k) l += (e >= kOff[k]);     // branchless level find
        const int i = e - kOff[l];
        const unsigned h = (((unsigned)i * P1) ^ ((unsigned)l * P2)) & HMASK;
        sTab[e] = *(const f32x4*)(tables + ((size_t)l * HSZ + h) * FEAT);
    }
    __syncthreads();

    const int tid    = blockIdx.x * blockDim.x + threadIdx.x;
    const int stride = GRID * BLOCK;                  // multiple of 16

    // level is loop-invariant (stride % 16 == 0): hoist per-level constants
    const int      l     = tid & 15;
    const bool     glob  = (l == 15);                 // finest level: global path
    const int      res   = kRes[l];
    const float    resm1 = (float)(res - 1);
    const int      imax  = res - 1;
    const int      soff  = glob ? 0 : kOff[l];
    const unsigned lh    = (unsigned)l * P2;
    const float*   t15   = tables + (size_t)15 * HSZ * FEAT;

    const int total = B * LVL;
    for (int idx = tid; idx < total; idx += stride) {
        const int p = idx >> 4;                       // point index

        float xc = x[p];
        xc = fminf(fmaxf(xc, 0.0f), 1.0f);

        const float t  = xc * resm1;                  // fp32, same as reference
        const float fi = floorf(t);
        const int   i0 = (int)fi;
        const int   i1 = min(i0 + 1, imax);
        const float w  = t - fi;

        f32x4 e0, e1;
        if (!glob) {                                  // 60/64 lanes: dense LDS
            e0 = sTab[soff + i0];
            e1 = sTab[soff + i1];
        } else {                                      // 4/64 lanes: L2-resident gather
            const unsigned h0 = (((unsigned)i0 * P1) ^ lh) & HMASK;
            const unsigned h1 = (((unsigned)i1 * P1) ^ lh) & HMASK;
            e0 = *(const f32x4*)(t15 + (size_t)h0 * FEAT);
            e1 = *(const f32x4*)(t15 + (size_t)h1 * FEAT);
        }

        const float omw = 1.0f - w;
        const f32x4 r = e0 * omw + e1 * w;

        // wave writes 1 KiB contiguous; NT: don't thrash L2 with the write stream
        __builtin_nontemporal_store(r, (f32x4*)(out + (size_t)idx * FEAT));
    }
}

extern "C" void kernel_launch(void* const* d_in, const int* in_sizes, int n_in,
                              void* d_out, int out_size, void* d_ws, size_t ws_size,
                              hipStream_t stream)
{
    const float* x      = (const float*)d_in[0];
    const float* tables = (const float*)d_in[1];
    float*       out    = (float*)d_out;
    const int    B      = in_sizes[0];                // 2097152

    hipLaunchKernelGGL(hashgrid1d_kernel, dim3(GRID), dim3(BLOCK), 0, stream,
                       x, tables, out, B);
}